// Round 1
// baseline (16.607 us; speedup 1.0000x reference)
//
#include <hip/hip_runtime.h>
#include <stdint.h>

#define I_DIM   256
#define O_DIM   256
#define K_DIM   1024
#define MT      64
#define NT      64
#define IC      16      // i's per K-chunk (BK = 64 = IC*4)
#define NCHUNK  16

typedef float f32x4 __attribute__((ext_vector_type(4)));
typedef short bf16x8 __attribute__((ext_vector_type(8)));

__device__ __forceinline__ uint32_t f2bf(float f) {
    // round-to-nearest-even f32 -> bf16 (values here are finite, no NaN path needed)
    uint32_t u = __builtin_bit_cast(uint32_t, f);
    u += 0x7fffu + ((u >> 16) & 1u);
    return u >> 16;
}

__device__ __forceinline__ float fast_tanh(float v) {
    float e = __expf(2.0f * v);
    return 1.0f - 2.0f / (e + 1.0f);
}

// T0..T3 of clip(tanh(v)) packed as 2x u32 (4 bf16, k ascending)
__device__ __forceinline__ void basis_words(float v, uint32_t& lo, uint32_t& hi) {
    const float CLIP = 0.99999994f;  // float32(1 - 1e-7) = nextafter(1,0)
    float t = fast_tanh(v);
    t = fminf(CLIP, fmaxf(-CLIP, t));
    float t2 = __builtin_fmaf(2.0f * t, t, -1.0f);
    float t3 = __builtin_fmaf(2.0f * t, t2, -t);
    lo = 0x3f80u | (f2bf(t) << 16);     // T0=1.0, T1=t
    hi = f2bf(t2) | (f2bf(t3) << 16);   // T2, T3
}

__global__ __launch_bounds__(256) void cheby_mfma(
        const float* __restrict__ x, const float* __restrict__ cc,
        float* __restrict__ out) {
    // LDS: As [64 rows][64 k] bf16 at 0..8191, Bs [64 cols][64 k] bf16 at 8192..16383
    // both XOR-swizzled: byte ^= (row&7)<<4  (breaks the 128B-stride 32-way conflict)
    __shared__ __align__(16) unsigned char lds[16384];

    const int tid  = threadIdx.x;
    const int lane = tid & 63;
    const int wid  = tid >> 6;
    const int bm   = blockIdx.x >> 2;
    const int bn   = blockIdx.x & 3;
    const int m0   = bm * MT;
    const int n0   = bn * NT;

    // A-staging assignment: thread -> (row, float4-of-x)
    const int arow = tid >> 2;   // 0..63
    const int aiq  = tid & 3;    // 0..3
    // B-staging assignment: thread -> (o column, base i-offset)
    const int bo   = tid & 63;   // 0..63
    const int bil  = tid >> 6;   // 0..3

    const float4* __restrict__ x4 = reinterpret_cast<const float4*>(x);
    const float4* __restrict__ c4 = reinterpret_cast<const float4*>(cc);

    auto loadc = [&](int ch, float4& XA, float4& A_, float4& B_, float4& C_, float4& D_) {
        const int ic0 = ch * IC;
        XA = x4[(m0 + arow) * (I_DIM / 4) + (ic0 >> 2) + aiq];
        A_ = c4[(ic0 + bil +  0) * O_DIM + n0 + bo];  // float4 = C[i][o][0..3]
        B_ = c4[(ic0 + bil +  4) * O_DIM + n0 + bo];
        C_ = c4[(ic0 + bil +  8) * O_DIM + n0 + bo];
        D_ = c4[(ic0 + bil + 12) * O_DIM + n0 + bo];
    };

    auto stage = [&](const float4& XA, const float4& A_, const float4& B_,
                     const float4& C_, const float4& D_) {
        // A: 4 x-values -> 16 bf16 (k = aiq*16 .. +15), two 16B swizzled writes
        uint32_t l0, h0, l1, h1, l2, h2, l3, h3;
        basis_words(XA.x, l0, h0);
        basis_words(XA.y, l1, h1);
        basis_words(XA.z, l2, h2);
        basis_words(XA.w, l3, h3);
        const uint32_t abase = (uint32_t)(arow * 128 + aiq * 32);
        const uint32_t axor  = (uint32_t)((arow & 7) << 4);
        *reinterpret_cast<uint4*>(lds + ((abase     ) ^ axor)) = make_uint4(l0, h0, l1, h1);
        *reinterpret_cast<uint4*>(lds + ((abase + 16) ^ axor)) = make_uint4(l2, h2, l3, h3);
        // B: each float4 = 4 consecutive k at column bo -> one 8B swizzled write
        auto stb = [&](const float4& V, int il) {
            uint32_t u0 = f2bf(V.x) | (f2bf(V.y) << 16);
            uint32_t u1 = f2bf(V.z) | (f2bf(V.w) << 16);
            uint32_t off = 8192u + (uint32_t)(((bo * 128) + il * 8) ^ ((bo & 7) << 4));
            *reinterpret_cast<uint2*>(lds + off) = make_uint2(u0, u1);
        };
        stb(A_, bil);
        stb(B_, bil + 4);
        stb(C_, bil + 8);
        stb(D_, bil + 12);
    };

    f32x4 acc00 = {0.f, 0.f, 0.f, 0.f};
    f32x4 acc01 = {0.f, 0.f, 0.f, 0.f};
    f32x4 acc10 = {0.f, 0.f, 0.f, 0.f};
    f32x4 acc11 = {0.f, 0.f, 0.f, 0.f};

    const int mrow  = (wid >> 1) * 32 + (lane & 15);  // A row for this lane's a-frag
    const int bcol  = (wid & 1) * 32 + (lane & 15);   // B col for this lane's b-frag
    const int klane = (lane >> 4) << 3;               // k sub-offset (0,8,16,24)

    float4 xa, cbA, cbB, cbC, cbD;
    loadc(0, xa, cbA, cbB, cbC, cbD);

    for (int ch = 0; ch < NCHUNK; ++ch) {
        stage(xa, cbA, cbB, cbC, cbD);
        __syncthreads();

        float4 nxa, nA, nB, nC, nD;
        const int nch = (ch + 1) & (NCHUNK - 1);
        loadc(nch, nxa, nA, nB, nC, nD);  // in flight under MFMA

        #pragma unroll
        for (int ks = 0; ks < 2; ++ks) {
            const int kb = ks * 32 + klane;  // bf16 index within the 64-wide chunk
            const uint32_t ao0 = (uint32_t)(((mrow     ) * 128 + kb * 2) ^ (((mrow     ) & 7) << 4));
            const uint32_t ao1 = (uint32_t)(((mrow + 16) * 128 + kb * 2) ^ (((mrow + 16) & 7) << 4));
            const uint32_t bo0 = 8192u + (uint32_t)(((bcol     ) * 128 + kb * 2) ^ (((bcol     ) & 7) << 4));
            const uint32_t bo1 = 8192u + (uint32_t)(((bcol + 16) * 128 + kb * 2) ^ (((bcol + 16) & 7) << 4));
            bf16x8 a0 = *reinterpret_cast<const bf16x8*>(lds + ao0);
            bf16x8 a1 = *reinterpret_cast<const bf16x8*>(lds + ao1);
            bf16x8 b0 = *reinterpret_cast<const bf16x8*>(lds + bo0);
            bf16x8 b1 = *reinterpret_cast<const bf16x8*>(lds + bo1);
            acc00 = __builtin_amdgcn_mfma_f32_16x16x32_bf16(a0, b0, acc00, 0, 0, 0);
            acc01 = __builtin_amdgcn_mfma_f32_16x16x32_bf16(a0, b1, acc01, 0, 0, 0);
            acc10 = __builtin_amdgcn_mfma_f32_16x16x32_bf16(a1, b0, acc10, 0, 0, 0);
            acc11 = __builtin_amdgcn_mfma_f32_16x16x32_bf16(a1, b1, acc11, 0, 0, 0);
        }
        __syncthreads();

        xa = nxa; cbA = nA; cbB = nB; cbC = nC; cbD = nD;
    }

    // Epilogue: C/D layout col=lane&15, row=(lane>>4)*4+reg  [guide §3, m89-verified]
    const float sc  = 1.0f / 256.0f;
    const int crow = (lane >> 4) << 2;
    const int ccol = lane & 15;
    const int gb = m0 + (wid >> 1) * 32 + crow;
    const int go = n0 + (wid & 1) * 32 + ccol;
    #pragma unroll
    for (int r = 0; r < 4; ++r) {
        out[(gb + r)      * O_DIM + go     ] = acc00[r] * sc;
        out[(gb + r)      * O_DIM + go + 16] = acc01[r] * sc;
        out[(gb + 16 + r) * O_DIM + go     ] = acc10[r] * sc;
        out[(gb + 16 + r) * O_DIM + go + 16] = acc11[r] * sc;
    }
}

extern "C" void kernel_launch(void* const* d_in, const int* in_sizes, int n_in,
                              void* d_out, int out_size, void* d_ws, size_t ws_size,
                              hipStream_t stream) {
    const float* x  = (const float*)d_in[0];
    const float* cc = (const float*)d_in[1];
    float* out = (float*)d_out;
    // grid: 32 M-tiles x 4 N-tiles = 128 blocks, 256 threads (4 waves)
    cheby_mfma<<<dim3(128), dim3(256), 0, stream>>>(x, cc, out);
}

// Round 2
// 14.414 us; speedup vs baseline: 1.1521x; 1.1521x over previous
//
#include <hip/hip_runtime.h>
#include <stdint.h>

#define I_DIM   256
#define O_DIM   256
#define BM      32
#define BN      32
#define NCH     4      // K chunks: BK=256 (=64 i-values) each

typedef float f32x4 __attribute__((ext_vector_type(4)));
typedef short bf16x8 __attribute__((ext_vector_type(8)));

__device__ __forceinline__ uint32_t f2bf(float f) {
    uint32_t u = __builtin_bit_cast(uint32_t, f);
    u += 0x7fffu + ((u >> 16) & 1u);
    return u >> 16;
}

__device__ __forceinline__ float fast_tanh(float v) {
    float e = __expf(2.0f * v);
    return 1.0f - 2.0f / (e + 1.0f);
}

// T0..T3 of clip(tanh(v)) packed as 2x u32 (4 bf16, k ascending)
__device__ __forceinline__ void basis_words(float v, uint32_t& lo, uint32_t& hi) {
    const float CLIP = 0.99999994f;  // nextafter(1,0)
    float t = fast_tanh(v);
    t = fminf(CLIP, fmaxf(-CLIP, t));
    float t2 = __builtin_fmaf(2.0f * t, t, -1.0f);
    float t3 = __builtin_fmaf(2.0f * t, t2, -t);
    lo = 0x3f80u | (f2bf(t) << 16);     // T0=1.0, T1=t
    hi = f2bf(t2) | (f2bf(t3) << 16);   // T2, T3
}

// LDS map: A[d]: d*16384 + row*512 + kbyte       (row 0..31, kbyte 0..511)
//          B[d]: 32768 + d*16384 + col*512 + kbyte
// both XOR-swizzled with ^((row&31)<<4) — frag reads 2-way (free)
__global__ __launch_bounds__(256, 2) void cheby_mfma(
        const float* __restrict__ x, const float* __restrict__ cc,
        float* __restrict__ out) {
    __shared__ __align__(16) unsigned char lds[65536];

    const int tid  = threadIdx.x;
    const int lane = tid & 63;
    const int wid  = tid >> 6;
    const int bm   = blockIdx.x >> 3;   // 64 M-tiles
    const int bn   = blockIdx.x & 7;    // 8 N-tiles
    const int m0   = bm * BM;
    const int n0   = bn * BN;

    // staging assignments
    const int arow = tid >> 3;          // 0..31  (A row)
    const int aiq  = tid & 7;           // 0..7   (pair of x-float4s)
    const int bcl  = tid & 31;          // 0..31  (B col)
    const int big  = tid >> 5;          // 0..7   (group of 8 i's)

    const float4* __restrict__ x4 = reinterpret_cast<const float4*>(x);
    const float4* __restrict__ c4 = reinterpret_cast<const float4*>(cc);

    float4 ax0, ax1;                    // x prefetch (8 values)
    float4 cb[8];                       // coeff prefetch (8 float4)

    auto loadAB = [&](int ch) {
        const float4* p = &x4[(m0 + arow) * (I_DIM / 4) + ch * 16 + aiq * 2];
        ax0 = p[0]; ax1 = p[1];
        #pragma unroll
        for (int j = 0; j < 8; ++j)
            cb[j] = c4[(ch * 64 + big * 8 + j) * O_DIM + n0 + bcl];
    };

    auto stageAB = [&](int d) {
        // A: 8 x-values -> 32 bf16, kbytes [aiq*64, aiq*64+64)
        const uint32_t abase = (uint32_t)(d * 16384 + arow * 512 + aiq * 64);
        const uint32_t axr   = (uint32_t)((arow & 31) << 4);
        uint32_t w0, w1, w2, w3, w4, w5, w6, w7;
        basis_words(ax0.x, w0, w1); basis_words(ax0.y, w2, w3);
        basis_words(ax0.z, w4, w5); basis_words(ax0.w, w6, w7);
        *reinterpret_cast<uint4*>(lds + ((abase     ) ^ axr)) = make_uint4(w0, w1, w2, w3);
        *reinterpret_cast<uint4*>(lds + ((abase + 16) ^ axr)) = make_uint4(w4, w5, w6, w7);
        basis_words(ax1.x, w0, w1); basis_words(ax1.y, w2, w3);
        basis_words(ax1.z, w4, w5); basis_words(ax1.w, w6, w7);
        *reinterpret_cast<uint4*>(lds + ((abase + 32) ^ axr)) = make_uint4(w0, w1, w2, w3);
        *reinterpret_cast<uint4*>(lds + ((abase + 48) ^ axr)) = make_uint4(w4, w5, w6, w7);
        // B: 8 float4 (= i big*8..big*8+7, 4 d each) -> 32 bf16, kbytes [big*64, +64)
        const uint32_t bbase = (uint32_t)(32768 + d * 16384 + bcl * 512 + big * 64);
        const uint32_t bxr   = (uint32_t)((bcl & 31) << 4);
        #pragma unroll
        for (int j = 0; j < 8; j += 2) {
            uint32_t u0 = f2bf(cb[j].x)     | (f2bf(cb[j].y) << 16);
            uint32_t u1 = f2bf(cb[j].z)     | (f2bf(cb[j].w) << 16);
            uint32_t u2 = f2bf(cb[j + 1].x) | (f2bf(cb[j + 1].y) << 16);
            uint32_t u3 = f2bf(cb[j + 1].z) | (f2bf(cb[j + 1].w) << 16);
            *reinterpret_cast<uint4*>(lds + ((bbase + j * 8) ^ bxr)) = make_uint4(u0, u1, u2, u3);
        }
    };

    // compute: each wave owns one 16x16 quadrant (wr, wc), full K
    const int wr = wid >> 1, wc = wid & 1;
    const int mrow  = wr * 16 + (lane & 15);
    const int bcol  = wc * 16 + (lane & 15);
    const int klane = (lane >> 4) << 3;
    const uint32_t aswz = (uint32_t)((mrow & 31) << 4);
    const uint32_t bswz = (uint32_t)((bcol & 31) << 4);

    f32x4 acc0 = {0.f, 0.f, 0.f, 0.f};
    f32x4 acc1 = {0.f, 0.f, 0.f, 0.f};

    loadAB(0);
    #pragma unroll
    for (int ch = 0; ch < NCH; ++ch) {
        stageAB(ch & 1);
        if (ch + 1 < NCH) loadAB(ch + 1);   // in flight across barrier + compute
        __syncthreads();
        const uint32_t abase = (uint32_t)((ch & 1) * 16384 + mrow * 512);
        const uint32_t bbase = (uint32_t)(32768 + (ch & 1) * 16384 + bcol * 512);
        #pragma unroll
        for (int ks = 0; ks < 8; ++ks) {
            const uint32_t kb = (uint32_t)((ks * 32 + klane) * 2);
            bf16x8 a = *reinterpret_cast<const bf16x8*>(lds + ((abase + kb) ^ aswz));
            bf16x8 b = *reinterpret_cast<const bf16x8*>(lds + ((bbase + kb) ^ bswz));
            if (ks & 1) acc1 = __builtin_amdgcn_mfma_f32_16x16x32_bf16(a, b, acc1, 0, 0, 0);
            else        acc0 = __builtin_amdgcn_mfma_f32_16x16x32_bf16(a, b, acc0, 0, 0, 0);
        }
        // one barrier per chunk is sufficient with double buffering: the buffer
        // stage(ch+2) overwrites was last read at compute(ch), ordered by the
        // barrier inside iteration ch+1.
        if (ch + 1 < NCH) __syncthreads();
    }

    // Epilogue: C/D layout col=lane&15, row=(lane>>4)*4+reg [m89-verified]
    const float sc = 1.0f / 256.0f;
    f32x4 r = (acc0 + acc1);
    const int gr = m0 + wr * 16 + ((lane >> 4) << 2);
    const int gc = n0 + wc * 16 + (lane & 15);
    #pragma unroll
    for (int q = 0; q < 4; ++q)
        out[(gr + q) * O_DIM + gc] = r[q] * sc;
}

extern "C" void kernel_launch(void* const* d_in, const int* in_sizes, int n_in,
                              void* d_out, int out_size, void* d_ws, size_t ws_size,
                              hipStream_t stream) {
    (void)in_sizes; (void)n_in; (void)out_size; (void)d_ws; (void)ws_size;
    const float* x  = (const float*)d_in[0];
    const float* cc = (const float*)d_in[1];
    float* out = (float*)d_out;
    // 64 M-tiles x 8 N-tiles = 512 blocks, 256 threads (4 waves), 2 blocks/CU
    cheby_mfma<<<dim3(512), dim3(256), 0, stream>>>(x, cc, out);
}